// Round 1
// baseline (4248.601 us; speedup 1.0000x reference)
//
#include <hip/hip_runtime.h>

static constexpr int NN = 100000;   // nodes
static constexpr int EE = 1600000;  // edges (before self-loops)

// ---------------- degree / norm precompute ----------------

__global__ __launch_bounds__(256) void k_deg(const int* __restrict__ dst,
                                             float* __restrict__ deg, int E) {
    int i = blockIdx.x * 256 + threadIdx.x;
    if (i < E) unsafeAtomicAdd(&deg[dst[i]], 1.0f);
}

__global__ __launch_bounds__(256) void k_dinv(float* __restrict__ deg, int n) {
    int i = blockIdx.x * 256 + threadIdx.x;
    if (i < n) deg[i] = rsqrtf(deg[i] + 1.0f);  // +1 for self-loop; deg>=1 always
}

__global__ __launch_bounds__(256) void k_norm(const int* __restrict__ src,
                                              const int* __restrict__ dst,
                                              const float* __restrict__ dinv,
                                              float* __restrict__ norm, int E) {
    int i = blockIdx.x * 256 + threadIdx.x;
    if (i < E) norm[i] = dinv[src[i]] * dinv[dst[i]];
}

// ---------------- fp32 GEMM: H[M,NC] = X[M,128] @ W[128,NC] ----------------
// Block: 256 threads, TM=64 rows. Thread computes RPT rows x 4 cols.
// X tile staged in LDS (32 KB), W rows read as coalesced float4 from L1/L2.

template<int NC, int RPT>
__global__ __launch_bounds__(256) void k_gemm(const float* __restrict__ X,
                                              const float* __restrict__ W,
                                              float* __restrict__ H, int M) {
    constexpr int CT = NC / 4;        // col-threads (32 or 16)
    constexpr int RG = 256 / CT;      // row groups
    constexpr int TM = RG * RPT;      // rows per block (64)
    __shared__ float xs[TM * 128];
    const int t = threadIdx.x;
    const int row0 = blockIdx.x * TM;

    // stage X tile, coalesced float4
    for (int idx = t; idx < TM * 32; idx += 256) {
        int r = idx >> 5, c = idx & 31;
        float4 v = make_float4(0.f, 0.f, 0.f, 0.f);
        if (row0 + r < M) v = ((const float4*)(X + (size_t)(row0 + r) * 128))[c];
        ((float4*)xs)[idx] = v;
    }
    __syncthreads();

    const int tc = t % CT;
    const int tr = t / CT;
    float acc[RPT][4];
#pragma unroll
    for (int i = 0; i < RPT; ++i) {
        acc[i][0] = 0.f; acc[i][1] = 0.f; acc[i][2] = 0.f; acc[i][3] = 0.f;
    }
    const float4* __restrict__ Wv = (const float4*)W;  // W[k][NC] as float4 rows
#pragma unroll 4
    for (int k = 0; k < 128; k += 4) {
        float4 w0 = Wv[(k + 0) * CT + tc];
        float4 w1 = Wv[(k + 1) * CT + tc];
        float4 w2 = Wv[(k + 2) * CT + tc];
        float4 w3 = Wv[(k + 3) * CT + tc];
#pragma unroll
        for (int rr = 0; rr < RPT; ++rr) {
            const float4 xv = *((const float4*)(xs + (tr * RPT + rr) * 128 + k));
            acc[rr][0] = fmaf(xv.x, w0.x, fmaf(xv.y, w1.x, fmaf(xv.z, w2.x, fmaf(xv.w, w3.x, acc[rr][0]))));
            acc[rr][1] = fmaf(xv.x, w0.y, fmaf(xv.y, w1.y, fmaf(xv.z, w2.y, fmaf(xv.w, w3.y, acc[rr][1]))));
            acc[rr][2] = fmaf(xv.x, w0.z, fmaf(xv.y, w1.z, fmaf(xv.z, w2.z, fmaf(xv.w, w3.z, acc[rr][2]))));
            acc[rr][3] = fmaf(xv.x, w0.w, fmaf(xv.y, w1.w, fmaf(xv.z, w2.w, fmaf(xv.w, w3.w, acc[rr][3]))));
        }
    }
#pragma unroll
    for (int rr = 0; rr < RPT; ++rr) {
        int r = row0 + tr * RPT + rr;
        if (r < M)
            ((float4*)(H + (size_t)r * NC))[tc] =
                make_float4(acc[rr][0], acc[rr][1], acc[rr][2], acc[rr][3]);
    }
}

// ---------------- sparse aggregation (scatter-add with HW fp32 atomics) ----------------
// D/4 threads per edge; each thread handles one float4 chunk of the message.

template<int D>
__global__ __launch_bounds__(256) void k_agg(const int* __restrict__ src,
                                             const int* __restrict__ dst,
                                             const float* __restrict__ norm,
                                             const float* __restrict__ H,
                                             float* __restrict__ AGG, int E) {
    constexpr int C = D / 4;
    int tid = blockIdx.x * 256 + threadIdx.x;
    int e = tid / C;
    if (e >= E) return;
    int c = tid % C;
    int s = src[e], d = dst[e];
    float nv = norm[e];
    const float4 hv = ((const float4*)(H + (size_t)s * D))[c];
    float* o = AGG + (size_t)d * D + c * 4;
    unsafeAtomicAdd(o + 0, hv.x * nv);
    unsafeAtomicAdd(o + 1, hv.y * nv);
    unsafeAtomicAdd(o + 2, hv.z * nv);
    unsafeAtomicAdd(o + 3, hv.w * nv);
}

// ---------------- epilogue: self-loop term + bias (+ relu) ----------------

template<int D, bool RELU>
__global__ __launch_bounds__(256) void k_epi(const float* __restrict__ AGG,
                                             const float* __restrict__ H,
                                             const float* __restrict__ dinv,
                                             const float* __restrict__ bias,
                                             float* __restrict__ OUT, int n) {
    constexpr int C = D / 4;
    int tid = blockIdx.x * 256 + threadIdx.x;
    int i = tid / C;
    if (i >= n) return;
    int c = tid % C;
    float di = dinv[i];
    float sl = di * di;                 // self-loop norm = dinv[i]^2
    float4 a = ((const float4*)AGG)[tid];
    float4 h = ((const float4*)H)[tid];
    float4 bv = ((const float4*)bias)[c];
    float4 r;
    r.x = fmaf(h.x, sl, a.x) + bv.x;
    r.y = fmaf(h.y, sl, a.y) + bv.y;
    r.z = fmaf(h.z, sl, a.z) + bv.z;
    r.w = fmaf(h.w, sl, a.w) + bv.w;
    if (RELU) {
        r.x = fmaxf(r.x, 0.f); r.y = fmaxf(r.y, 0.f);
        r.z = fmaxf(r.z, 0.f); r.w = fmaxf(r.w, 0.f);
    }
    ((float4*)OUT)[tid] = r;
}

// ---------------- launch ----------------

extern "C" void kernel_launch(void* const* d_in, const int* in_sizes, int n_in,
                              void* d_out, int out_size, void* d_ws, size_t ws_size,
                              hipStream_t stream) {
    const float* x  = (const float*)d_in[0];
    const float* W1 = (const float*)d_in[1];
    const float* b1 = (const float*)d_in[2];
    const float* W2 = (const float*)d_in[3];
    const float* b2 = (const float*)d_in[4];
    const int*   ei = (const int*)d_in[5];   // [2, E] int32
    const int* src = ei;
    const int* dst = ei + EE;
    float* out = (float*)d_out;

    // workspace layout (fp32), buffers reused:
    //   deg/dinv: N | norm: E | h1: N*128 | agg1: N*128 (becomes hrelu in place)
    //   h2 overlays h1[0:N*64), agg2 overlays h1[N*64:N*128)  -- h1 dead after epi1
    float* deg  = (float*)d_ws;                 // N
    float* norm = deg + NN;                     // E
    float* h1   = norm + EE;                    // N*128
    float* agg1 = h1 + (size_t)NN * 128;        // N*128
    float* h2   = h1;                           // N*64 (reuse)
    float* agg2 = h1 + (size_t)NN * 64;         // N*64 (reuse)

    hipMemsetAsync(deg, 0, NN * sizeof(float), stream);
    k_deg<<<(EE + 255) / 256, 256, 0, stream>>>(dst, deg, EE);
    k_dinv<<<(NN + 255) / 256, 256, 0, stream>>>(deg, NN);
    k_norm<<<(EE + 255) / 256, 256, 0, stream>>>(src, dst, deg, norm, EE);

    // layer 1: h1 = x @ W1 ; agg1 = scatter(norm * h1[src]) ; hrelu = relu(agg1 + dinv^2*h1 + b1)
    k_gemm<128, 8><<<(NN + 63) / 64, 256, 0, stream>>>(x, W1, h1, NN);
    hipMemsetAsync(agg1, 0, (size_t)NN * 128 * sizeof(float), stream);
    k_agg<128><<<(EE * 32) / 256, 256, 0, stream>>>(src, dst, norm, h1, agg1, EE);
    k_epi<128, true><<<(NN * 128 / 4) / 256, 256, 0, stream>>>(agg1, h1, deg, b1, agg1, NN);

    // layer 2: h2 = hrelu @ W2 ; agg2 = scatter(norm * h2[src]) ; out = agg2 + dinv^2*h2 + b2
    k_gemm<64, 4><<<(NN + 63) / 64, 256, 0, stream>>>(agg1, W2, h2, NN);
    hipMemsetAsync(agg2, 0, (size_t)NN * 64 * sizeof(float), stream);
    k_agg<64><<<(EE * 16) / 256, 256, 0, stream>>>(src, dst, norm, h2, agg2, EE);
    k_epi<64, false><<<(NN * 64 / 4) / 256, 256, 0, stream>>>(agg2, h2, deg, b2, out, NN);
}

// Round 2
// 623.984 us; speedup vs baseline: 6.8088x; 6.8088x over previous
//
#include <hip/hip_runtime.h>

static constexpr int NN = 100000;   // nodes
static constexpr int EE = 1600000;  // edges (before self-loops)
static constexpr int NCH = (NN + 511) / 512;  // scan chunks (512 elems each)

// ---------------- degree histogram / dinv ----------------

__global__ __launch_bounds__(256) void k_count(const int* __restrict__ dst,
                                               int* __restrict__ cnt, int E) {
    int i = blockIdx.x * 256 + threadIdx.x;
    if (i < E) atomicAdd(&cnt[dst[i]], 1);
}

__global__ __launch_bounds__(256) void k_dinv(const int* __restrict__ cnt,
                                              float* __restrict__ dinv, int n) {
    int i = blockIdx.x * 256 + threadIdx.x;
    if (i < n) dinv[i] = rsqrtf((float)cnt[i] + 1.0f);  // +1 self-loop
}

// ---------------- exclusive scan of cnt -> rowptr (3-phase) ----------------

__global__ __launch_bounds__(256) void k_scan1(const int* __restrict__ cnt,
                                               int* __restrict__ rowptr,
                                               int* __restrict__ csum, int n) {
    __shared__ int sd[256];
    const int c = blockIdx.x, t = threadIdx.x;
    const int i0 = c * 512 + t * 2;
    int a0 = (i0 < n) ? cnt[i0] : 0;
    int a1 = (i0 + 1 < n) ? cnt[i0 + 1] : 0;
    int p = a0 + a1;
    sd[t] = p;
    __syncthreads();
    for (int off = 1; off < 256; off <<= 1) {
        int v = (t >= off) ? sd[t - off] : 0;
        __syncthreads();
        sd[t] += v;
        __syncthreads();
    }
    int exc = (t == 0) ? 0 : sd[t - 1];
    if (i0 < n) rowptr[i0] = exc;
    if (i0 + 1 < n) rowptr[i0 + 1] = exc + a0;
    if (t == 255) csum[c] = sd[255];
}

__global__ __launch_bounds__(256) void k_scan2(int* __restrict__ csum, int m) {
    __shared__ int sd[256];
    const int t = threadIdx.x;
    sd[t] = (t < m) ? csum[t] : 0;
    __syncthreads();
    for (int off = 1; off < 256; off <<= 1) {
        int v = (t >= off) ? sd[t - off] : 0;
        __syncthreads();
        sd[t] += v;
        __syncthreads();
    }
    if (t < m) csum[t] = (t == 0) ? 0 : sd[t - 1];
}

__global__ __launch_bounds__(256) void k_scan3(int* __restrict__ rowptr,
                                               const int* __restrict__ csum, int n) {
    int i = blockIdx.x * 256 + threadIdx.x;
    if (i < n) rowptr[i] += csum[i >> 9];
}

// ---------------- CSR fill (bumps rowptr; afterwards rowptr[d] = end of d) --

__global__ __launch_bounds__(256) void k_fill(const int* __restrict__ src,
                                              const int* __restrict__ dst,
                                              int* __restrict__ rowptr,
                                              int* __restrict__ csr_src, int E) {
    int e = blockIdx.x * 256 + threadIdx.x;
    if (e < E) {
        int pos = atomicAdd(&rowptr[dst[e]], 1);
        csr_src[pos] = src[e];
    }
}

// ---------------- fp32 GEMM with fused row scale: G = (X @ W) * dinv[row] ---

template<int NC, int RPT>
__global__ __launch_bounds__(256) void k_gemm(const float* __restrict__ X,
                                              const float* __restrict__ W,
                                              const float* __restrict__ dinv,
                                              float* __restrict__ G, int M) {
    constexpr int CT = NC / 4;        // col-threads (32 or 16)
    constexpr int RG = 256 / CT;      // row groups
    constexpr int TM = RG * RPT;      // rows per block (64)
    __shared__ float xs[TM * 128];
    const int t = threadIdx.x;
    const int row0 = blockIdx.x * TM;

    for (int idx = t; idx < TM * 32; idx += 256) {
        int r = idx >> 5, c = idx & 31;
        float4 v = make_float4(0.f, 0.f, 0.f, 0.f);
        if (row0 + r < M) v = ((const float4*)(X + (size_t)(row0 + r) * 128))[c];
        ((float4*)xs)[idx] = v;
    }
    __syncthreads();

    const int tc = t % CT;
    const int tr = t / CT;
    float acc[RPT][4];
#pragma unroll
    for (int i = 0; i < RPT; ++i) {
        acc[i][0] = 0.f; acc[i][1] = 0.f; acc[i][2] = 0.f; acc[i][3] = 0.f;
    }
    const float4* __restrict__ Wv = (const float4*)W;
#pragma unroll 4
    for (int k = 0; k < 128; k += 4) {
        float4 w0 = Wv[(k + 0) * CT + tc];
        float4 w1 = Wv[(k + 1) * CT + tc];
        float4 w2 = Wv[(k + 2) * CT + tc];
        float4 w3 = Wv[(k + 3) * CT + tc];
#pragma unroll
        for (int rr = 0; rr < RPT; ++rr) {
            const float4 xv = *((const float4*)(xs + (tr * RPT + rr) * 128 + k));
            acc[rr][0] = fmaf(xv.x, w0.x, fmaf(xv.y, w1.x, fmaf(xv.z, w2.x, fmaf(xv.w, w3.x, acc[rr][0]))));
            acc[rr][1] = fmaf(xv.x, w0.y, fmaf(xv.y, w1.y, fmaf(xv.z, w2.y, fmaf(xv.w, w3.y, acc[rr][1]))));
            acc[rr][2] = fmaf(xv.x, w0.z, fmaf(xv.y, w1.z, fmaf(xv.z, w2.z, fmaf(xv.w, w3.z, acc[rr][2]))));
            acc[rr][3] = fmaf(xv.x, w0.w, fmaf(xv.y, w1.w, fmaf(xv.z, w2.w, fmaf(xv.w, w3.w, acc[rr][3]))));
        }
    }
#pragma unroll
    for (int rr = 0; rr < RPT; ++rr) {
        int r = row0 + tr * RPT + rr;
        if (r < M) {
            float s = dinv[r];
            ((float4*)(G + (size_t)r * NC))[tc] =
                make_float4(acc[rr][0] * s, acc[rr][1] * s, acc[rr][2] * s, acc[rr][3] * s);
        }
    }
}

// ---------------- gather aggregation: AGG[d] = sum over incoming g[src] -----
// One wave per node; a wave reads one full g-row coalesced per edge.
// rowptr is post-fill (shifted): end(d) = rowptr[d], beg(d) = rowptr[d-1].

template<int D>
__global__ __launch_bounds__(256) void k_gather(const int* __restrict__ rowptr,
                                                const int* __restrict__ csr_src,
                                                const float* __restrict__ G,
                                                float* __restrict__ AGG, int n) {
    const int node = blockIdx.x * 4 + (threadIdx.x >> 6);
    if (node >= n) return;
    const int lane = threadIdx.x & 63;
    const int beg = (node == 0) ? 0 : rowptr[node - 1];
    const int end = rowptr[node];

    if constexpr (D == 128) {
        const float2* __restrict__ Gv = (const float2*)G;
        float2 a0 = make_float2(0.f, 0.f), a1 = make_float2(0.f, 0.f);
        int j = beg;
        for (; j + 2 <= end; j += 2) {
            int s0 = csr_src[j], s1 = csr_src[j + 1];
            float2 v0 = Gv[(size_t)s0 * 64 + lane];
            float2 v1 = Gv[(size_t)s1 * 64 + lane];
            a0.x += v0.x; a0.y += v0.y;
            a1.x += v1.x; a1.y += v1.y;
        }
        if (j < end) {
            float2 v0 = Gv[(size_t)csr_src[j] * 64 + lane];
            a0.x += v0.x; a0.y += v0.y;
        }
        a0.x += a1.x; a0.y += a1.y;
        ((float2*)AGG)[(size_t)node * 64 + lane] = a0;
    } else {
        float a0 = 0.f, a1 = 0.f;
        int j = beg;
        for (; j + 2 <= end; j += 2) {
            int s0 = csr_src[j], s1 = csr_src[j + 1];
            a0 += G[(size_t)s0 * 64 + lane];
            a1 += G[(size_t)s1 * 64 + lane];
        }
        if (j < end) a0 += G[(size_t)csr_src[j] * 64 + lane];
        AGG[(size_t)node * 64 + lane] = a0 + a1;
    }
}

// ---------------- epilogue: out = dinv[i]*(acc + g[i]) + b (+relu) ----------

template<int D, bool RELU>
__global__ __launch_bounds__(256) void k_epi(const float* __restrict__ AGG,
                                             const float* __restrict__ G,
                                             const float* __restrict__ dinv,
                                             const float* __restrict__ bias,
                                             float* __restrict__ OUT, int n) {
    constexpr int C = D / 4;
    int tid = blockIdx.x * 256 + threadIdx.x;
    int i = tid / C;
    if (i >= n) return;
    int c = tid % C;
    float di = dinv[i];
    float4 a = ((const float4*)AGG)[tid];
    float4 g = ((const float4*)G)[tid];
    float4 bv = ((const float4*)bias)[c];
    float4 r;
    r.x = fmaf(a.x + g.x, di, bv.x);
    r.y = fmaf(a.y + g.y, di, bv.y);
    r.z = fmaf(a.z + g.z, di, bv.z);
    r.w = fmaf(a.w + g.w, di, bv.w);
    if (RELU) {
        r.x = fmaxf(r.x, 0.f); r.y = fmaxf(r.y, 0.f);
        r.z = fmaxf(r.z, 0.f); r.w = fmaxf(r.w, 0.f);
    }
    ((float4*)OUT)[tid] = r;
}

// ---------------- launch ----------------

extern "C" void kernel_launch(void* const* d_in, const int* in_sizes, int n_in,
                              void* d_out, int out_size, void* d_ws, size_t ws_size,
                              hipStream_t stream) {
    const float* x  = (const float*)d_in[0];
    const float* W1 = (const float*)d_in[1];
    const float* b1 = (const float*)d_in[2];
    const float* W2 = (const float*)d_in[3];
    const float* b2 = (const float*)d_in[4];
    const int*   ei = (const int*)d_in[5];   // [2, E] int32
    const int* src = ei;
    const int* dst = ei + EE;
    float* out = (float*)d_out;

    // ws layout (4-byte words):
    //   cnt: N int | dinv: N f | rowptr: N int | csum: 256 int | csr_src: E int
    //   g1: N*128 f | agg1: N*128 f (becomes hrelu in place)
    //   g2 overlays g1[0:N*64), agg2 overlays g1[N*64:N*128)  (g1 dead after epi1)
    int*   cnt    = (int*)d_ws;                        // N
    float* dinv   = (float*)d_ws + NN;                 // N
    int*   rowptr = (int*)d_ws + 2 * NN;               // N
    int*   csum   = (int*)d_ws + 3 * NN;               // 256
    int*   csr    = (int*)d_ws + 3 * NN + 256;         // E
    float* g1     = (float*)d_ws + 3 * NN + 256 + EE;  // N*128
    float* agg1   = g1 + (size_t)NN * 128;             // N*128
    float* g2     = g1;                                // N*64 (reuse)
    float* agg2   = g1 + (size_t)NN * 64;              // N*64 (reuse)

    // CSR build + dinv
    hipMemsetAsync(cnt, 0, NN * sizeof(int), stream);
    k_count<<<(EE + 255) / 256, 256, 0, stream>>>(dst, cnt, EE);
    k_dinv<<<(NN + 255) / 256, 256, 0, stream>>>(cnt, dinv, NN);
    k_scan1<<<NCH, 256, 0, stream>>>(cnt, rowptr, csum, NN);
    k_scan2<<<1, 256, 0, stream>>>(csum, NCH);
    k_scan3<<<(NN + 255) / 256, 256, 0, stream>>>(rowptr, csum, NN);
    k_fill<<<(EE + 255) / 256, 256, 0, stream>>>(src, dst, rowptr, csr, EE);

    // layer 1
    k_gemm<128, 8><<<(NN + 63) / 64, 256, 0, stream>>>(x, W1, dinv, g1, NN);
    k_gather<128><<<(NN + 3) / 4, 256, 0, stream>>>(rowptr, csr, g1, agg1, NN);
    k_epi<128, true><<<(NN * 32 + 255) / 256, 256, 0, stream>>>(agg1, g1, dinv, b1, agg1, NN);

    // layer 2
    k_gemm<64, 4><<<(NN + 63) / 64, 256, 0, stream>>>(agg1, W2, dinv, g2, NN);
    k_gather<64><<<(NN + 3) / 4, 256, 0, stream>>>(rowptr, csr, g2, agg2, NN);
    k_epi<64, false><<<(NN * 16 + 255) / 256, 256, 0, stream>>>(agg2, g2, dinv, b2, out, NN);
}